// Round 7
// baseline (194.528 us; speedup 1.0000x reference)
//
#include <hip/hip_runtime.h>
#include <math.h>

#define TOKS 16384
#define CDIM 128
#define NH 4
#define HD 32
#define HID 512
#define QSCALE 0.17677669529663687f
#define LEPS 1e-5f

typedef const float* fp;
typedef __attribute__((ext_vector_type(8))) short bf16x8;
typedef __attribute__((ext_vector_type(4))) float f32x4;

__device__ inline unsigned int bfp2(float a, float b) {
    unsigned int ua = __float_as_uint(a); ua = (ua + 0x7FFFu + ((ua >> 16) & 1u)) >> 16;
    unsigned int ub = __float_as_uint(b); ub = (ub + 0x7FFFu + ((ub >> 16) & 1u)) >> 16;
    return ua | (ub << 16);
}
__device__ inline unsigned short bf1(float a) {
    unsigned int u = __float_as_uint(a);
    return (unsigned short)((u + 0x7FFFu + ((u >> 16) & 1u)) >> 16);
}
__device__ inline float lo16(unsigned int u) { return __uint_as_float(u << 16); }
__device__ inline float hi16(unsigned int u) { return __uint_as_float(u & 0xFFFF0000u); }

// ---------------- k0: LN row stats (mean, rstd) — used for LN1(x) and LN2(h) ----------------
__global__ __launch_bounds__(256) void k0_stats(fp x, float* __restrict__ stats1) {
    const int t = threadIdx.x;
    const int row = blockIdx.x * 8 + (t >> 5);
    const int l = t & 31;
    const float4 v = *(const float4*)(x + (size_t)row * CDIM + l * 4);
    float s = v.x + v.y + v.z + v.w;
    float q = v.x * v.x + v.y * v.y + v.z * v.z + v.w * v.w;
#pragma unroll
    for (int m = 16; m >= 1; m >>= 1) { s += __shfl_xor(s, m); q += __shfl_xor(q, m); }
    if (l == 0) {
        float mu = s * (1.f / 128.f);
        float var = q * (1.f / 128.f) - mu * mu;
        stats1[row * 2] = mu;
        stats1[row * 2 + 1] = rsqrtf(var + LEPS);
    }
}

// ================= MFMA GEMM kernels =================
// Tile: 64(M) x 64(N), 256 threads = 4 waves, each wave 16 rows x 4 n-tiles.
// LDS: A[64 rows][64 dwords] bf16 + Bt[64 n][64 dwords] bf16, 16B-chunk XOR swizzle.

// ---------------- k1: LN1-apply + QKV GEMM (K=128, N=384); Q->f32, K/V->bf16 ----------------
__global__ __launch_bounds__(256) void k1_mfma(fp x, fp stats1, fp g, fp b, fp w, fp wb,
                                               float* __restrict__ qb,
                                               unsigned short* __restrict__ kvb) {
    __shared__ unsigned int lds[8192];
    const int m0 = blockIdx.x * 64;
    const int nb = blockIdx.y * 64;
    const int tid = threadIdx.x;
#pragma unroll
    for (int i = 0; i < 8; i++) {
        int slot = tid + i * 256;
        int m = slot >> 5, f4 = slot & 31, k0 = f4 * 4;
        const float4 xv = *(const float4*)(x + (size_t)(m0 + m) * CDIM + k0);
        float mu = stats1[(m0 + m) * 2], rs = stats1[(m0 + m) * 2 + 1];
        const float4 gv = *(const float4*)(g + k0);
        const float4 bv = *(const float4*)(b + k0);
        float a0 = (xv.x - mu) * rs * gv.x + bv.x, a1 = (xv.y - mu) * rs * gv.y + bv.y;
        float a2 = (xv.z - mu) * rs * gv.z + bv.z, a3 = (xv.w - mu) * rs * gv.w + bv.w;
        unsigned int* p = &lds[m * 64 + ((f4 >> 1) ^ (m & 15)) * 4 + (f4 & 1) * 2];
        p[0] = bfp2(a0, a1); p[1] = bfp2(a2, a3);
    }
#pragma unroll
    for (int i = 0; i < 16; i++) {
        int idx = tid + i * 256;
        int n = idx & 63, kp = idx >> 6, k = kp * 2;
        float b0 = w[(size_t)k * 384 + nb + n];
        float b1v = w[(size_t)(k + 1) * 384 + nb + n];
        lds[4096 + n * 64 + ((k >> 3) ^ (n & 15)) * 4 + ((k >> 1) & 3)] = bfp2(b0, b1v);
    }
    __syncthreads();

    const int lane = tid & 63, wid = tid >> 6, quad = lane >> 4, l16 = lane & 15;
    const int mrow = wid * 16 + l16;
    f32x4 acc[4];
#pragma unroll
    for (int nt = 0; nt < 4; nt++) acc[nt] = (f32x4){0.f, 0.f, 0.f, 0.f};
#pragma unroll
    for (int kk = 0; kk < 128; kk += 32) {
        int c = (kk >> 3) + quad;
        bf16x8 a = *(bf16x8*)&lds[mrow * 64 + (c ^ l16) * 4];
#pragma unroll
        for (int nt = 0; nt < 4; nt++) {
            bf16x8 bf = *(bf16x8*)&lds[4096 + (nt * 16 + l16) * 64 + (c ^ l16) * 4];
            acc[nt] = __builtin_amdgcn_mfma_f32_16x16x32_bf16(a, bf, acc[nt], 0, 0, 0);
        }
    }
#pragma unroll
    for (int nt = 0; nt < 4; nt++) {
        int col = nb + nt * 16 + l16;
        float bias = wb[col];
#pragma unroll
        for (int r = 0; r < 4; r++) {
            int row = m0 + wid * 16 + quad * 4 + r;
            float vres = acc[nt][r] + bias;
            if (col < 128)
                qb[(size_t)row * 128 + col] = vres * QSCALE;
            else if (col < 256)
                kvb[(size_t)row * 256 + (col - 128)] = bf1(vres);
            else
                kvb[(size_t)row * 256 + 128 + (col - 256)] = bf1(vres);
        }
    }
}

// ---------------- k2: neighborhood attention, 4 lanes per (token, head), bf16 K/V ----------
__global__ __launch_bounds__(256) void k2_attn(const float* __restrict__ qb,
                                               const unsigned short* __restrict__ kvb,
                                               fp rpb, unsigned short* __restrict__ attnb) {
    const int gid = blockIdx.x * 256 + threadIdx.x;   // 262144
    const int d = gid & 3;
    const int head = (gid >> 2) & 3;
    const int token = gid >> 4;
    const int bb = token >> 12;
    const int y = (token >> 6) & 63;
    const int xx = token & 63;
    const int sy = min(max(y - 3, 0), 57);
    const int sx = min(max(xx - 3, 0), 57);

    const int koff = head * HD + d * 8;               // element offset within 128
    float q[8];
    {
        const float4* qp = (const float4*)(qb + (size_t)token * 128 + koff);
        float4 q0 = qp[0], q1 = qp[1];
        q[0] = q0.x; q[1] = q0.y; q[2] = q0.z; q[3] = q0.w;
        q[4] = q1.x; q[5] = q1.y; q[6] = q1.z; q[7] = q1.w;
    }

    float sc[49];
    const float* rp = rpb + head * 169 + (sy - y + 6) * 13 + (sx - xx + 6);
    const int nbase = (bb << 12) + sy * 64 + sx;
#pragma unroll
    for (int dy = 0; dy < 7; dy++) {
#pragma unroll
        for (int dx = 0; dx < 7; dx++) {
            const uint4 kk = *(const uint4*)(kvb + (size_t)(nbase + dy * 64 + dx) * 256 + koff);
            float s = q[0] * lo16(kk.x) + q[1] * hi16(kk.x)
                    + q[2] * lo16(kk.y) + q[3] * hi16(kk.y)
                    + q[4] * lo16(kk.z) + q[5] * hi16(kk.z)
                    + q[6] * lo16(kk.w) + q[7] * hi16(kk.w);
            s += __shfl_xor(s, 1);
            s += __shfl_xor(s, 2);
            sc[dy * 7 + dx] = s + rp[dy * 13 + dx];
        }
    }
    float mx = sc[0];
#pragma unroll
    for (int l = 1; l < 49; l++) mx = fmaxf(mx, sc[l]);
    float sum = 0.f;
#pragma unroll
    for (int l = 0; l < 49; l++) { sc[l] = __expf(sc[l] - mx); sum += sc[l]; }
    float inv = 1.f / sum;

    float o[8];
#pragma unroll
    for (int i = 0; i < 8; i++) o[i] = 0.f;
#pragma unroll
    for (int dy = 0; dy < 7; dy++) {
#pragma unroll
        for (int dx = 0; dx < 7; dx++) {
            float p = sc[dy * 7 + dx] * inv;
            const uint4 vv = *(const uint4*)(kvb + (size_t)(nbase + dy * 64 + dx) * 256 + 128 + koff);
            o[0] += p * lo16(vv.x); o[1] += p * hi16(vv.x);
            o[2] += p * lo16(vv.y); o[3] += p * hi16(vv.y);
            o[4] += p * lo16(vv.z); o[5] += p * hi16(vv.z);
            o[6] += p * lo16(vv.w); o[7] += p * hi16(vv.w);
        }
    }
    uint4 ov;
    ov.x = bfp2(o[0], o[1]); ov.y = bfp2(o[2], o[3]);
    ov.z = bfp2(o[4], o[5]); ov.w = bfp2(o[6], o[7]);
    *(uint4*)(attnb + (size_t)token * 128 + koff) = ov;
}

// ---------------- k3: proj GEMM (K=128, N=128) + residual -> h ----------------
__global__ __launch_bounds__(256) void k3_mfma(const unsigned short* __restrict__ attnb,
                                               fp x, fp w, fp wb, float* __restrict__ h) {
    __shared__ unsigned int lds[8192];
    const int m0 = blockIdx.x * 64;
    const int nb = blockIdx.y * 64;
    const int tid = threadIdx.x;
    // A stage: bf16 direct copy (1024 uint4 = 64 rows x 16 chunks)
#pragma unroll
    for (int i = 0; i < 4; i++) {
        int slot = tid + i * 256;
        int m = slot >> 4, c16 = slot & 15;
        const uint4 v4 = *(const uint4*)(attnb + (size_t)(m0 + m) * 128 + c16 * 8);
        *(uint4*)&lds[m * 64 + (c16 ^ (m & 15)) * 4] = v4;
    }
#pragma unroll
    for (int i = 0; i < 16; i++) {
        int idx = tid + i * 256;
        int n = idx & 63, kp = idx >> 6, k = kp * 2;
        float b0 = w[(size_t)k * CDIM + nb + n];
        float b1v = w[(size_t)(k + 1) * CDIM + nb + n];
        lds[4096 + n * 64 + ((k >> 3) ^ (n & 15)) * 4 + ((k >> 1) & 3)] = bfp2(b0, b1v);
    }
    __syncthreads();

    const int lane = tid & 63, wid = tid >> 6, quad = lane >> 4, l16 = lane & 15;
    const int mrow = wid * 16 + l16;
    f32x4 acc[4];
#pragma unroll
    for (int nt = 0; nt < 4; nt++) acc[nt] = (f32x4){0.f, 0.f, 0.f, 0.f};
#pragma unroll
    for (int kk = 0; kk < 128; kk += 32) {
        int c = (kk >> 3) + quad;
        bf16x8 a = *(bf16x8*)&lds[mrow * 64 + (c ^ l16) * 4];
#pragma unroll
        for (int nt = 0; nt < 4; nt++) {
            bf16x8 bf = *(bf16x8*)&lds[4096 + (nt * 16 + l16) * 64 + (c ^ l16) * 4];
            acc[nt] = __builtin_amdgcn_mfma_f32_16x16x32_bf16(a, bf, acc[nt], 0, 0, 0);
        }
    }
#pragma unroll
    for (int nt = 0; nt < 4; nt++) {
        int col = nb + nt * 16 + l16;
        float bias = wb[col];
#pragma unroll
        for (int r = 0; r < 4; r++) {
            int row = m0 + wid * 16 + quad * 4 + r;
            h[(size_t)row * CDIM + col] = x[(size_t)row * CDIM + col] + acc[nt][r] + bias;
        }
    }
}

// ---------------- k4: LN2-apply + fc1 + GELU (K=128, N=512) -> y1 bf16 ----------------
__global__ __launch_bounds__(256) void k4_mfma(fp h, fp stats, fp g, fp b, fp w, fp wb,
                                               unsigned short* __restrict__ y1) {
    __shared__ unsigned int lds[8192];
    const int m0 = blockIdx.x * 64;
    const int nb = blockIdx.y * 64;
    const int tid = threadIdx.x;
#pragma unroll
    for (int i = 0; i < 8; i++) {
        int slot = tid + i * 256;
        int m = slot >> 5, f4 = slot & 31, k0 = f4 * 4;
        const float4 xv = *(const float4*)(h + (size_t)(m0 + m) * CDIM + k0);
        float mu = stats[(m0 + m) * 2], rs = stats[(m0 + m) * 2 + 1];
        const float4 gv = *(const float4*)(g + k0);
        const float4 bv = *(const float4*)(b + k0);
        float a0 = (xv.x - mu) * rs * gv.x + bv.x, a1 = (xv.y - mu) * rs * gv.y + bv.y;
        float a2 = (xv.z - mu) * rs * gv.z + bv.z, a3 = (xv.w - mu) * rs * gv.w + bv.w;
        unsigned int* p = &lds[m * 64 + ((f4 >> 1) ^ (m & 15)) * 4 + (f4 & 1) * 2];
        p[0] = bfp2(a0, a1); p[1] = bfp2(a2, a3);
    }
#pragma unroll
    for (int i = 0; i < 16; i++) {
        int idx = tid + i * 256;
        int n = idx & 63, kp = idx >> 6, k = kp * 2;
        float b0 = w[(size_t)k * HID + nb + n];
        float b1v = w[(size_t)(k + 1) * HID + nb + n];
        lds[4096 + n * 64 + ((k >> 3) ^ (n & 15)) * 4 + ((k >> 1) & 3)] = bfp2(b0, b1v);
    }
    __syncthreads();

    const int lane = tid & 63, wid = tid >> 6, quad = lane >> 4, l16 = lane & 15;
    const int mrow = wid * 16 + l16;
    f32x4 acc[4];
#pragma unroll
    for (int nt = 0; nt < 4; nt++) acc[nt] = (f32x4){0.f, 0.f, 0.f, 0.f};
#pragma unroll
    for (int kk = 0; kk < 128; kk += 32) {
        int c = (kk >> 3) + quad;
        bf16x8 a = *(bf16x8*)&lds[mrow * 64 + (c ^ l16) * 4];
#pragma unroll
        for (int nt = 0; nt < 4; nt++) {
            bf16x8 bf = *(bf16x8*)&lds[4096 + (nt * 16 + l16) * 64 + (c ^ l16) * 4];
            acc[nt] = __builtin_amdgcn_mfma_f32_16x16x32_bf16(a, bf, acc[nt], 0, 0, 0);
        }
    }
#pragma unroll
    for (int nt = 0; nt < 4; nt++) {
        int col = nb + nt * 16 + l16;
        float bias = wb[col];
#pragma unroll
        for (int r = 0; r < 4; r++) {
            int row = m0 + wid * 16 + quad * 4 + r;
            float z = acc[nt][r] + bias;
            y1[(size_t)row * HID + col] = bf1(0.5f * z * (1.f + erff(z * 0.70710678118654752f)));
        }
    }
}

// ---------------- k5: fc2 + residual (K=512 in 4 chunks, N=128), y1 bf16 in ----------------
__global__ __launch_bounds__(256) void k5_mfma(const unsigned short* __restrict__ y1,
                                               fp h, fp w, fp wb, float* __restrict__ out) {
    __shared__ unsigned int lds[8192];
    const int m0 = blockIdx.x * 64;
    const int nb = blockIdx.y * 64;
    const int tid = threadIdx.x;
    const int lane = tid & 63, wid = tid >> 6, quad = lane >> 4, l16 = lane & 15;
    const int mrow = wid * 16 + l16;
    f32x4 acc[4];
#pragma unroll
    for (int nt = 0; nt < 4; nt++) acc[nt] = (f32x4){0.f, 0.f, 0.f, 0.f};

    for (int kc = 0; kc < 4; kc++) {
        if (kc) __syncthreads();
#pragma unroll
        for (int i = 0; i < 4; i++) {
            int slot = tid + i * 256;
            int m = slot >> 4, c16 = slot & 15;
            const uint4 v4 = *(const uint4*)(y1 + (size_t)(m0 + m) * HID + kc * 128 + c16 * 8);
            *(uint4*)&lds[m * 64 + (c16 ^ (m & 15)) * 4] = v4;
        }
#pragma unroll
        for (int i = 0; i < 16; i++) {
            int idx = tid + i * 256;
            int n = idx & 63, kp = idx >> 6, k = kp * 2;
            float b0 = w[(size_t)(kc * 128 + k) * CDIM + nb + n];
            float b1v = w[(size_t)(kc * 128 + k + 1) * CDIM + nb + n];
            lds[4096 + n * 64 + ((k >> 3) ^ (n & 15)) * 4 + ((k >> 1) & 3)] = bfp2(b0, b1v);
        }
        __syncthreads();
#pragma unroll
        for (int kk = 0; kk < 128; kk += 32) {
            int c = (kk >> 3) + quad;
            bf16x8 a = *(bf16x8*)&lds[mrow * 64 + (c ^ l16) * 4];
#pragma unroll
            for (int nt = 0; nt < 4; nt++) {
                bf16x8 bf = *(bf16x8*)&lds[4096 + (nt * 16 + l16) * 64 + (c ^ l16) * 4];
                acc[nt] = __builtin_amdgcn_mfma_f32_16x16x32_bf16(a, bf, acc[nt], 0, 0, 0);
            }
        }
    }
#pragma unroll
    for (int nt = 0; nt < 4; nt++) {
        int col = nb + nt * 16 + l16;
        float bias = wb[col];
#pragma unroll
        for (int r = 0; r < 4; r++) {
            int row = m0 + wid * 16 + quad * 4 + r;
            out[(size_t)row * CDIM + col] = h[(size_t)row * CDIM + col] + acc[nt][r] + bias;
        }
    }
}

extern "C" void kernel_launch(void* const* d_in, const int* in_sizes, int n_in,
                              void* d_out, int out_size, void* d_ws, size_t ws_size,
                              hipStream_t stream) {
    fp x      = (fp)d_in[0];
    fp ln1_g  = (fp)d_in[1];
    fp ln1_b  = (fp)d_in[2];
    fp qkv_w  = (fp)d_in[3];
    fp qkv_b  = (fp)d_in[4];
    fp rpb    = (fp)d_in[5];
    fp proj_w = (fp)d_in[6];
    fp proj_b = (fp)d_in[7];
    fp ln2_g  = (fp)d_in[8];
    fp ln2_b  = (fp)d_in[9];
    fp fc1_w  = (fp)d_in[10];
    fp fc1_b  = (fp)d_in[11];
    fp fc2_w  = (fp)d_in[12];
    fp fc2_b  = (fp)d_in[13];
    float* out = (float*)d_out;

    // workspace layout:
    //   h      f32  [TOKS][128]   8 MB
    //   stats  f32  [TOKS][2]     (LN2)
    //   stats1 f32  [TOKS][2]     (LN1)
    //   qb     f32  [TOKS][128]   8 MB   (dead after k2)
    //   kvb    bf16 [TOKS][256]   8 MB   (dead after k2)
    //   attnb  bf16 [TOKS][128]   4 MB   (dead after k3)
    //   y1     bf16 [TOKS][512]  16 MB   aliases qb+kvb
    float* ws     = (float*)d_ws;
    float* h      = ws;
    float* stats  = h + (size_t)TOKS * CDIM;
    float* stats1 = stats + (size_t)TOKS * 2;
    float* qb     = stats1 + (size_t)TOKS * 2;
    unsigned short* kvb   = (unsigned short*)(qb + (size_t)TOKS * CDIM);
    unsigned short* attnb = kvb + (size_t)TOKS * 256;
    unsigned short* y1    = (unsigned short*)qb;

    k0_stats<<<TOKS / 8, 256, 0, stream>>>(x, stats1);
    k1_mfma<<<dim3(TOKS / 64, 6), 256, 0, stream>>>(x, stats1, ln1_g, ln1_b, qkv_w, qkv_b, qb, kvb);
    k2_attn<<<TOKS * NH * 4 / 256, 256, 0, stream>>>(qb, kvb, rpb, attnb);
    k3_mfma<<<dim3(TOKS / 64, 2), 256, 0, stream>>>(attnb, x, proj_w, proj_b, h);
    k0_stats<<<TOKS / 8, 256, 0, stream>>>(h, stats);
    k4_mfma<<<dim3(TOKS / 64, 8), 256, 0, stream>>>(h, stats, ln2_g, ln2_b, fc1_w, fc1_b, y1);
    k5_mfma<<<dim3(TOKS / 64, 2), 256, 0, stream>>>(y1, h, fc2_w, fc2_b, out);
}

// Round 9
// 170.860 us; speedup vs baseline: 1.1385x; 1.1385x over previous
//
#include <hip/hip_runtime.h>
#include <math.h>

#define TOKS 16384
#define CDIM 128
#define NH 4
#define HD 32
#define HID 512
#define QSCALE 0.17677669529663687f
#define LEPS 1e-5f

typedef const float* fp;
typedef __attribute__((ext_vector_type(8))) short bf16x8;
typedef __attribute__((ext_vector_type(4))) float f32x4;

__device__ inline unsigned int bfp2(float a, float b) {
    unsigned int ua = __float_as_uint(a); ua = (ua + 0x7FFFu + ((ua >> 16) & 1u)) >> 16;
    unsigned int ub = __float_as_uint(b); ub = (ub + 0x7FFFu + ((ub >> 16) & 1u)) >> 16;
    return ua | (ub << 16);
}
__device__ inline unsigned short bf1(float a) {
    unsigned int u = __float_as_uint(a);
    return (unsigned short)((u + 0x7FFFu + ((u >> 16) & 1u)) >> 16);
}
__device__ inline float lo16(unsigned int u) { return __uint_as_float(u << 16); }
__device__ inline float hi16(unsigned int u) { return __uint_as_float(u & 0xFFFF0000u); }

// ---------------- k0: LN row stats (mean, rstd) — used for LN1(x) and LN2(h) ----------------
__global__ __launch_bounds__(256) void k0_stats(fp x, float* __restrict__ stats1) {
    const int t = threadIdx.x;
    const int row = blockIdx.x * 8 + (t >> 5);
    const int l = t & 31;
    const float4 v = *(const float4*)(x + (size_t)row * CDIM + l * 4);
    float s = v.x + v.y + v.z + v.w;
    float q = v.x * v.x + v.y * v.y + v.z * v.z + v.w * v.w;
#pragma unroll
    for (int m = 16; m >= 1; m >>= 1) { s += __shfl_xor(s, m); q += __shfl_xor(q, m); }
    if (l == 0) {
        float mu = s * (1.f / 128.f);
        float var = q * (1.f / 128.f) - mu * mu;
        stats1[row * 2] = mu;
        stats1[row * 2 + 1] = rsqrtf(var + LEPS);
    }
}

// ================= MFMA GEMM kernels =================
// Tile: 64(M) x 64(N), 256 threads = 4 waves, each wave 16 rows x 4 n-tiles.
// LDS: A[64 rows][64 dwords] bf16 + Bt[64 n][64 dwords] bf16, 16B-chunk XOR swizzle.

// ---------------- k1: LN1-apply + QKV GEMM (K=128, N=384); Q->f32, K/V->bf16 ----------------
__global__ __launch_bounds__(256) void k1_mfma(fp x, fp stats1, fp g, fp b, fp w, fp wb,
                                               float* __restrict__ qb,
                                               unsigned short* __restrict__ kvb) {
    __shared__ unsigned int lds[8192];
    const int m0 = blockIdx.x * 64;
    const int nb = blockIdx.y * 64;
    const int tid = threadIdx.x;
#pragma unroll
    for (int i = 0; i < 8; i++) {
        int slot = tid + i * 256;
        int m = slot >> 5, f4 = slot & 31, k0 = f4 * 4;
        const float4 xv = *(const float4*)(x + (size_t)(m0 + m) * CDIM + k0);
        float mu = stats1[(m0 + m) * 2], rs = stats1[(m0 + m) * 2 + 1];
        const float4 gv = *(const float4*)(g + k0);
        const float4 bv = *(const float4*)(b + k0);
        float a0 = (xv.x - mu) * rs * gv.x + bv.x, a1 = (xv.y - mu) * rs * gv.y + bv.y;
        float a2 = (xv.z - mu) * rs * gv.z + bv.z, a3 = (xv.w - mu) * rs * gv.w + bv.w;
        unsigned int* p = &lds[m * 64 + ((f4 >> 1) ^ (m & 15)) * 4 + (f4 & 1) * 2];
        p[0] = bfp2(a0, a1); p[1] = bfp2(a2, a3);
    }
#pragma unroll
    for (int i = 0; i < 16; i++) {
        int idx = tid + i * 256;
        int n = idx & 63, kp = idx >> 6, k = kp * 2;
        float b0 = w[(size_t)k * 384 + nb + n];
        float b1v = w[(size_t)(k + 1) * 384 + nb + n];
        lds[4096 + n * 64 + ((k >> 3) ^ (n & 15)) * 4 + ((k >> 1) & 3)] = bfp2(b0, b1v);
    }
    __syncthreads();

    const int lane = tid & 63, wid = tid >> 6, quad = lane >> 4, l16 = lane & 15;
    const int mrow = wid * 16 + l16;
    f32x4 acc[4];
#pragma unroll
    for (int nt = 0; nt < 4; nt++) acc[nt] = (f32x4){0.f, 0.f, 0.f, 0.f};
#pragma unroll
    for (int kk = 0; kk < 128; kk += 32) {
        int c = (kk >> 3) + quad;
        bf16x8 a = *(bf16x8*)&lds[mrow * 64 + (c ^ l16) * 4];
#pragma unroll
        for (int nt = 0; nt < 4; nt++) {
            bf16x8 bf = *(bf16x8*)&lds[4096 + (nt * 16 + l16) * 64 + (c ^ l16) * 4];
            acc[nt] = __builtin_amdgcn_mfma_f32_16x16x32_bf16(a, bf, acc[nt], 0, 0, 0);
        }
    }
#pragma unroll
    for (int nt = 0; nt < 4; nt++) {
        int col = nb + nt * 16 + l16;
        float bias = wb[col];
#pragma unroll
        for (int r = 0; r < 4; r++) {
            int row = m0 + wid * 16 + quad * 4 + r;
            float vres = acc[nt][r] + bias;
            if (col < 128)
                qb[(size_t)row * 128 + col] = vres * QSCALE;
            else if (col < 256)
                kvb[(size_t)row * 256 + (col - 128)] = bf1(vres);
            else
                kvb[(size_t)row * 256 + 128 + (col - 256)] = bf1(vres);
        }
    }
}

// ---------------- k2: neighborhood attention, 16 lanes per (token, head) ----------------
// lane = (d, g): d=dims d*8..d*8+7, g=neighbor quarter (13 slots, 49 real).
// QK partial-dot reduced over d (shfl_xor 1,2); softmax + PV combined over g (shfl_xor 4,8).
__global__ __launch_bounds__(256) void k2_attn(const float* __restrict__ qb,
                                               const unsigned short* __restrict__ kvb,
                                               fp rpb, unsigned short* __restrict__ attnb) {
    const int gid = blockIdx.x * 256 + threadIdx.x;   // 1048576
    const int d = gid & 3;
    const int g = (gid >> 2) & 3;
    const int head = (gid >> 4) & 3;
    const int token = gid >> 6;
    const int bb = token >> 12;
    const int y = (token >> 6) & 63;
    const int xx = token & 63;
    const int sy = min(max(y - 3, 0), 57);
    const int sx = min(max(xx - 3, 0), 57);

    const int koff = head * HD + d * 8;               // element offset within 128
    float q[8];
    {
        const float4* qp = (const float4*)(qb + (size_t)token * 128 + koff);
        float4 q0 = qp[0], q1 = qp[1];
        q[0] = q0.x; q[1] = q0.y; q[2] = q0.z; q[3] = q0.w;
        q[4] = q1.x; q[5] = q1.y; q[6] = q1.z; q[7] = q1.w;
    }

    const float* rp = rpb + head * 169 + (sy - y + 6) * 13 + (sx - xx + 6);
    const int nbase = (bb << 12) + sy * 64 + sx;

    float sc[13];
#pragma unroll
    for (int i = 0; i < 13; i++) {
        int n = g * 13 + i;
        bool ok = n < 49;
        int nn = ok ? n : 48;
        int dy = nn / 7, dx = nn - dy * 7;
        const uint4 kk = *(const uint4*)(kvb + (size_t)(nbase + dy * 64 + dx) * 256 + koff);
        float s = q[0] * lo16(kk.x) + q[1] * hi16(kk.x)
                + q[2] * lo16(kk.y) + q[3] * hi16(kk.y)
                + q[4] * lo16(kk.z) + q[5] * hi16(kk.z)
                + q[6] * lo16(kk.w) + q[7] * hi16(kk.w);
        s += __shfl_xor(s, 1);
        s += __shfl_xor(s, 2);
        sc[i] = ok ? (s + rp[dy * 13 + dx]) : -1e30f;
    }
    float mx = sc[0];
#pragma unroll
    for (int l = 1; l < 13; l++) mx = fmaxf(mx, sc[l]);
    mx = fmaxf(mx, __shfl_xor(mx, 4));
    mx = fmaxf(mx, __shfl_xor(mx, 8));
    float sum = 0.f;
#pragma unroll
    for (int l = 0; l < 13; l++) { sc[l] = __expf(sc[l] - mx); sum += sc[l]; }
    sum += __shfl_xor(sum, 4);
    sum += __shfl_xor(sum, 8);
    float inv = 1.f / sum;

    float o[8];
#pragma unroll
    for (int i = 0; i < 8; i++) o[i] = 0.f;
#pragma unroll
    for (int i = 0; i < 13; i++) {
        int n = g * 13 + i;
        int nn = (n < 49) ? n : 48;
        int dy = nn / 7, dx = nn - dy * 7;
        float p = sc[i] * inv;                         // 0 for dummy slots
        const uint4 vv = *(const uint4*)(kvb + (size_t)(nbase + dy * 64 + dx) * 256 + 128 + koff);
        o[0] += p * lo16(vv.x); o[1] += p * hi16(vv.x);
        o[2] += p * lo16(vv.y); o[3] += p * hi16(vv.y);
        o[4] += p * lo16(vv.z); o[5] += p * hi16(vv.z);
        o[6] += p * lo16(vv.w); o[7] += p * hi16(vv.w);
    }
#pragma unroll
    for (int i = 0; i < 8; i++) {
        o[i] += __shfl_xor(o[i], 4);
        o[i] += __shfl_xor(o[i], 8);
    }
    if (g == 0) {
        uint4 ov;
        ov.x = bfp2(o[0], o[1]); ov.y = bfp2(o[2], o[3]);
        ov.z = bfp2(o[4], o[5]); ov.w = bfp2(o[6], o[7]);
        *(uint4*)(attnb + (size_t)token * 128 + koff) = ov;
    }
}

// ---------------- k3: proj GEMM (K=128, N=128) + residual -> h ----------------
__global__ __launch_bounds__(256) void k3_mfma(const unsigned short* __restrict__ attnb,
                                               fp x, fp w, fp wb, float* __restrict__ h) {
    __shared__ unsigned int lds[8192];
    const int m0 = blockIdx.x * 64;
    const int nb = blockIdx.y * 64;
    const int tid = threadIdx.x;
#pragma unroll
    for (int i = 0; i < 4; i++) {
        int slot = tid + i * 256;
        int m = slot >> 4, c16 = slot & 15;
        const uint4 v4 = *(const uint4*)(attnb + (size_t)(m0 + m) * 128 + c16 * 8);
        *(uint4*)&lds[m * 64 + (c16 ^ (m & 15)) * 4] = v4;
    }
#pragma unroll
    for (int i = 0; i < 16; i++) {
        int idx = tid + i * 256;
        int n = idx & 63, kp = idx >> 6, k = kp * 2;
        float b0 = w[(size_t)k * CDIM + nb + n];
        float b1v = w[(size_t)(k + 1) * CDIM + nb + n];
        lds[4096 + n * 64 + ((k >> 3) ^ (n & 15)) * 4 + ((k >> 1) & 3)] = bfp2(b0, b1v);
    }
    __syncthreads();

    const int lane = tid & 63, wid = tid >> 6, quad = lane >> 4, l16 = lane & 15;
    const int mrow = wid * 16 + l16;
    f32x4 acc[4];
#pragma unroll
    for (int nt = 0; nt < 4; nt++) acc[nt] = (f32x4){0.f, 0.f, 0.f, 0.f};
#pragma unroll
    for (int kk = 0; kk < 128; kk += 32) {
        int c = (kk >> 3) + quad;
        bf16x8 a = *(bf16x8*)&lds[mrow * 64 + (c ^ l16) * 4];
#pragma unroll
        for (int nt = 0; nt < 4; nt++) {
            bf16x8 bf = *(bf16x8*)&lds[4096 + (nt * 16 + l16) * 64 + (c ^ l16) * 4];
            acc[nt] = __builtin_amdgcn_mfma_f32_16x16x32_bf16(a, bf, acc[nt], 0, 0, 0);
        }
    }
#pragma unroll
    for (int nt = 0; nt < 4; nt++) {
        int col = nb + nt * 16 + l16;
        float bias = wb[col];
#pragma unroll
        for (int r = 0; r < 4; r++) {
            int row = m0 + wid * 16 + quad * 4 + r;
            h[(size_t)row * CDIM + col] = x[(size_t)row * CDIM + col] + acc[nt][r] + bias;
        }
    }
}

// ---------------- k4: LN2-apply + fc1 + GELU (K=128, N=512) -> y1 bf16 ----------------
__global__ __launch_bounds__(256) void k4_mfma(fp h, fp stats, fp g, fp b, fp w, fp wb,
                                               unsigned short* __restrict__ y1) {
    __shared__ unsigned int lds[8192];
    const int m0 = blockIdx.x * 64;
    const int nb = blockIdx.y * 64;
    const int tid = threadIdx.x;
#pragma unroll
    for (int i = 0; i < 8; i++) {
        int slot = tid + i * 256;
        int m = slot >> 5, f4 = slot & 31, k0 = f4 * 4;
        const float4 xv = *(const float4*)(h + (size_t)(m0 + m) * CDIM + k0);
        float mu = stats[(m0 + m) * 2], rs = stats[(m0 + m) * 2 + 1];
        const float4 gv = *(const float4*)(g + k0);
        const float4 bv = *(const float4*)(b + k0);
        float a0 = (xv.x - mu) * rs * gv.x + bv.x, a1 = (xv.y - mu) * rs * gv.y + bv.y;
        float a2 = (xv.z - mu) * rs * gv.z + bv.z, a3 = (xv.w - mu) * rs * gv.w + bv.w;
        unsigned int* p = &lds[m * 64 + ((f4 >> 1) ^ (m & 15)) * 4 + (f4 & 1) * 2];
        p[0] = bfp2(a0, a1); p[1] = bfp2(a2, a3);
    }
#pragma unroll
    for (int i = 0; i < 16; i++) {
        int idx = tid + i * 256;
        int n = idx & 63, kp = idx >> 6, k = kp * 2;
        float b0 = w[(size_t)k * HID + nb + n];
        float b1v = w[(size_t)(k + 1) * HID + nb + n];
        lds[4096 + n * 64 + ((k >> 3) ^ (n & 15)) * 4 + ((k >> 1) & 3)] = bfp2(b0, b1v);
    }
    __syncthreads();

    const int lane = tid & 63, wid = tid >> 6, quad = lane >> 4, l16 = lane & 15;
    const int mrow = wid * 16 + l16;
    f32x4 acc[4];
#pragma unroll
    for (int nt = 0; nt < 4; nt++) acc[nt] = (f32x4){0.f, 0.f, 0.f, 0.f};
#pragma unroll
    for (int kk = 0; kk < 128; kk += 32) {
        int c = (kk >> 3) + quad;
        bf16x8 a = *(bf16x8*)&lds[mrow * 64 + (c ^ l16) * 4];
#pragma unroll
        for (int nt = 0; nt < 4; nt++) {
            bf16x8 bf = *(bf16x8*)&lds[4096 + (nt * 16 + l16) * 64 + (c ^ l16) * 4];
            acc[nt] = __builtin_amdgcn_mfma_f32_16x16x32_bf16(a, bf, acc[nt], 0, 0, 0);
        }
    }
#pragma unroll
    for (int nt = 0; nt < 4; nt++) {
        int col = nb + nt * 16 + l16;
        float bias = wb[col];
#pragma unroll
        for (int r = 0; r < 4; r++) {
            int row = m0 + wid * 16 + quad * 4 + r;
            float z = acc[nt][r] + bias;
            y1[(size_t)row * HID + col] = bf1(0.5f * z * (1.f + erff(z * 0.70710678118654752f)));
        }
    }
}

// ---------------- k5: fc2 + residual (K=512 in 4 chunks, N=128), y1 bf16 in ----------------
__global__ __launch_bounds__(256) void k5_mfma(const unsigned short* __restrict__ y1,
                                               fp h, fp w, fp wb, float* __restrict__ out) {
    __shared__ unsigned int lds[8192];
    const int m0 = blockIdx.x * 64;
    const int nb = blockIdx.y * 64;
    const int tid = threadIdx.x;
    const int lane = tid & 63, wid = tid >> 6, quad = lane >> 4, l16 = lane & 15;
    const int mrow = wid * 16 + l16;
    f32x4 acc[4];
#pragma unroll
    for (int nt = 0; nt < 4; nt++) acc[nt] = (f32x4){0.f, 0.f, 0.f, 0.f};

    for (int kc = 0; kc < 4; kc++) {
        if (kc) __syncthreads();
#pragma unroll
        for (int i = 0; i < 4; i++) {
            int slot = tid + i * 256;
            int m = slot >> 4, c16 = slot & 15;
            const uint4 v4 = *(const uint4*)(y1 + (size_t)(m0 + m) * HID + kc * 128 + c16 * 8);
            *(uint4*)&lds[m * 64 + (c16 ^ (m & 15)) * 4] = v4;
        }
#pragma unroll
        for (int i = 0; i < 16; i++) {
            int idx = tid + i * 256;
            int n = idx & 63, kp = idx >> 6, k = kp * 2;
            float b0 = w[(size_t)(kc * 128 + k) * CDIM + nb + n];
            float b1v = w[(size_t)(kc * 128 + k + 1) * CDIM + nb + n];
            lds[4096 + n * 64 + ((k >> 3) ^ (n & 15)) * 4 + ((k >> 1) & 3)] = bfp2(b0, b1v);
        }
        __syncthreads();
#pragma unroll
        for (int kk = 0; kk < 128; kk += 32) {
            int c = (kk >> 3) + quad;
            bf16x8 a = *(bf16x8*)&lds[mrow * 64 + (c ^ l16) * 4];
#pragma unroll
            for (int nt = 0; nt < 4; nt++) {
                bf16x8 bf = *(bf16x8*)&lds[4096 + (nt * 16 + l16) * 64 + (c ^ l16) * 4];
                acc[nt] = __builtin_amdgcn_mfma_f32_16x16x32_bf16(a, bf, acc[nt], 0, 0, 0);
            }
        }
    }
#pragma unroll
    for (int nt = 0; nt < 4; nt++) {
        int col = nb + nt * 16 + l16;
        float bias = wb[col];
#pragma unroll
        for (int r = 0; r < 4; r++) {
            int row = m0 + wid * 16 + quad * 4 + r;
            out[(size_t)row * CDIM + col] = h[(size_t)row * CDIM + col] + acc[nt][r] + bias;
        }
    }
}

extern "C" void kernel_launch(void* const* d_in, const int* in_sizes, int n_in,
                              void* d_out, int out_size, void* d_ws, size_t ws_size,
                              hipStream_t stream) {
    fp x      = (fp)d_in[0];
    fp ln1_g  = (fp)d_in[1];
    fp ln1_b  = (fp)d_in[2];
    fp qkv_w  = (fp)d_in[3];
    fp qkv_b  = (fp)d_in[4];
    fp rpb    = (fp)d_in[5];
    fp proj_w = (fp)d_in[6];
    fp proj_b = (fp)d_in[7];
    fp ln2_g  = (fp)d_in[8];
    fp ln2_b  = (fp)d_in[9];
    fp fc1_w  = (fp)d_in[10];
    fp fc1_b  = (fp)d_in[11];
    fp fc2_w  = (fp)d_in[12];
    fp fc2_b  = (fp)d_in[13];
    float* out = (float*)d_out;

    float* ws     = (float*)d_ws;
    float* h      = ws;
    float* stats  = h + (size_t)TOKS * CDIM;
    float* stats1 = stats + (size_t)TOKS * 2;
    float* qb     = stats1 + (size_t)TOKS * 2;
    unsigned short* kvb   = (unsigned short*)(qb + (size_t)TOKS * CDIM);
    unsigned short* attnb = kvb + (size_t)TOKS * 256;
    unsigned short* y1    = (unsigned short*)qb;

    k0_stats<<<TOKS / 8, 256, 0, stream>>>(x, stats1);
    k1_mfma<<<dim3(TOKS / 64, 6), 256, 0, stream>>>(x, stats1, ln1_g, ln1_b, qkv_w, qkv_b, qb, kvb);
    k2_attn<<<TOKS * NH * 16 / 256, 256, 0, stream>>>(qb, kvb, rpb, attnb);
    k3_mfma<<<dim3(TOKS / 64, 2), 256, 0, stream>>>(attnb, x, proj_w, proj_b, h);
    k0_stats<<<TOKS / 8, 256, 0, stream>>>(h, stats);
    k4_mfma<<<dim3(TOKS / 64, 8), 256, 0, stream>>>(h, stats, ln2_g, ln2_b, fc1_w, fc1_b, y1);
    k5_mfma<<<dim3(TOKS / 64, 2), 256, 0, stream>>>(y1, h, fc2_w, fc2_b, out);
}

// Round 10
// 150.505 us; speedup vs baseline: 1.2925x; 1.1352x over previous
//
#include <hip/hip_runtime.h>
#include <math.h>

#define TOKS 16384
#define CDIM 128
#define NH 4
#define HD 32
#define HID 512
#define QSCALE 0.17677669529663687f
#define LEPS 1e-5f

typedef const float* fp;
typedef const unsigned short* bfp16;
typedef __attribute__((ext_vector_type(8))) short bf16x8;
typedef __attribute__((ext_vector_type(4))) float f32x4;

__device__ inline unsigned int bfp2(float a, float b) {
    unsigned int ua = __float_as_uint(a); ua = (ua + 0x7FFFu + ((ua >> 16) & 1u)) >> 16;
    unsigned int ub = __float_as_uint(b); ub = (ub + 0x7FFFu + ((ub >> 16) & 1u)) >> 16;
    return ua | (ub << 16);
}
__device__ inline unsigned short bf1(float a) {
    unsigned int u = __float_as_uint(a);
    return (unsigned short)((u + 0x7FFFu + ((u >> 16) & 1u)) >> 16);
}
__device__ inline float lo16(unsigned int u) { return __uint_as_float(u << 16); }
__device__ inline float hi16(unsigned int u) { return __uint_as_float(u & 0xFFFF0000u); }

// ---------------- kw: one-shot weight convert+transpose to bf16 [n][k] ----------------
// wt layout: [0,49152) qkv_wt[384][128]; [49152,65536) proj_wt[128][128];
//            [65536,131072) fc1_wt[512][128]; [131072,196608) fc2_wt[128][512].
__global__ __launch_bounds__(256) void kw(fp qw, fp pw, fp f1w, fp f2w,
                                          unsigned short* __restrict__ wt) {
    int e = blockIdx.x * 256 + threadIdx.x;
    float v;
    if (e < 49152)       { int n = e >> 7,  k = e & 127;          v = qw[(size_t)k * 384 + n]; }
    else if (e < 65536)  { int i = e - 49152;  int n = i >> 7, k = i & 127; v = pw[(size_t)k * 128 + n]; }
    else if (e < 131072) { int i = e - 65536;  int n = i >> 7, k = i & 127; v = f1w[(size_t)k * 512 + n]; }
    else                 { int i = e - 131072; int n = i >> 9, k = i & 511; v = f2w[(size_t)k * 128 + n]; }
    wt[e] = bf1(v);
}

// ---------------- k0_ln: row LN -> normalized bf16 activation ----------------
__global__ __launch_bounds__(256) void k0_ln(fp x, fp g, fp b, unsigned short* __restrict__ xn) {
    const int t = threadIdx.x;
    const int row = blockIdx.x * 8 + (t >> 5);
    const int l = t & 31;
    const float4 v = *(const float4*)(x + (size_t)row * CDIM + l * 4);
    float s = v.x + v.y + v.z + v.w;
    float q = v.x * v.x + v.y * v.y + v.z * v.z + v.w * v.w;
#pragma unroll
    for (int m = 16; m >= 1; m >>= 1) { s += __shfl_xor(s, m); q += __shfl_xor(q, m); }
    float mu = s * (1.f / 128.f);
    float rs = rsqrtf(q * (1.f / 128.f) - mu * mu + LEPS);
    const float4 gv = *(const float4*)(g + l * 4);
    const float4 bv = *(const float4*)(b + l * 4);
    float a0 = (v.x - mu) * rs * gv.x + bv.x, a1 = (v.y - mu) * rs * gv.y + bv.y;
    float a2 = (v.z - mu) * rs * gv.z + bv.z, a3 = (v.w - mu) * rs * gv.w + bv.w;
    uint2 o; o.x = bfp2(a0, a1); o.y = bfp2(a2, a3);
    *(uint2*)(xn + (size_t)row * CDIM + l * 4) = o;
}

// ================= MFMA GEMM kernels =================
// Tile: 64(M) x 64(N), 256 threads = 4 waves, each wave 16 rows x 4 n-tiles.
// LDS: A[64 m][64 dw] + Bt[64 n][64 dw] bf16, 16B-chunk XOR swizzle; all stages uint4 copies.

// ---------------- k1: QKV GEMM (A=xn bf16, K=128, N=384); Q->f32, K/V->bf16 ----------------
__global__ __launch_bounds__(256) void k1_mfma(bfp16 xn, bfp16 wt0, fp wb,
                                               float* __restrict__ qb,
                                               unsigned short* __restrict__ kvb) {
    __shared__ unsigned int lds[8192];
    const int m0 = blockIdx.x * 64;
    const int nb = blockIdx.y * 64;
    const int tid = threadIdx.x;
#pragma unroll
    for (int i = 0; i < 4; i++) {
        int slot = tid + i * 256;
        int m = slot >> 4, c16 = slot & 15;
        const uint4 v4 = *(const uint4*)(xn + (size_t)(m0 + m) * CDIM + c16 * 8);
        *(uint4*)&lds[m * 64 + (c16 ^ (m & 15)) * 4] = v4;
    }
#pragma unroll
    for (int i = 0; i < 4; i++) {
        int slot = tid + i * 256;
        int n = slot >> 4, c16 = slot & 15;
        const uint4 v4 = *(const uint4*)(wt0 + (size_t)(nb + n) * 128 + c16 * 8);
        *(uint4*)&lds[4096 + n * 64 + (c16 ^ (n & 15)) * 4] = v4;
    }
    __syncthreads();

    const int lane = tid & 63, wid = tid >> 6, quad = lane >> 4, l16 = lane & 15;
    const int mrow = wid * 16 + l16;
    f32x4 acc[4];
#pragma unroll
    for (int nt = 0; nt < 4; nt++) acc[nt] = (f32x4){0.f, 0.f, 0.f, 0.f};
#pragma unroll
    for (int kk = 0; kk < 128; kk += 32) {
        int c = (kk >> 3) + quad;
        bf16x8 a = *(bf16x8*)&lds[mrow * 64 + (c ^ l16) * 4];
#pragma unroll
        for (int nt = 0; nt < 4; nt++) {
            bf16x8 bf = *(bf16x8*)&lds[4096 + (nt * 16 + l16) * 64 + (c ^ l16) * 4];
            acc[nt] = __builtin_amdgcn_mfma_f32_16x16x32_bf16(a, bf, acc[nt], 0, 0, 0);
        }
    }
#pragma unroll
    for (int nt = 0; nt < 4; nt++) {
        int col = nb + nt * 16 + l16;
        float bias = wb[col];
#pragma unroll
        for (int r = 0; r < 4; r++) {
            int row = m0 + wid * 16 + quad * 4 + r;
            float vres = acc[nt][r] + bias;
            if (col < 128)
                qb[(size_t)row * 128 + col] = vres * QSCALE;
            else if (col < 256)
                kvb[(size_t)row * 256 + (col - 128)] = bf1(vres);
            else
                kvb[(size_t)row * 256 + 128 + (col - 256)] = bf1(vres);
        }
    }
}

// ---------------- k2: neighborhood attention, 16 lanes per (token, head) ----------------
__global__ __launch_bounds__(256) void k2_attn(const float* __restrict__ qb,
                                               const unsigned short* __restrict__ kvb,
                                               fp rpb, unsigned short* __restrict__ attnb) {
    const int gid = blockIdx.x * 256 + threadIdx.x;   // 1048576
    const int d = gid & 3;
    const int g = (gid >> 2) & 3;
    const int head = (gid >> 4) & 3;
    const int token = gid >> 6;
    const int bb = token >> 12;
    const int y = (token >> 6) & 63;
    const int xx = token & 63;
    const int sy = min(max(y - 3, 0), 57);
    const int sx = min(max(xx - 3, 0), 57);

    const int koff = head * HD + d * 8;
    float q[8];
    {
        const float4* qp = (const float4*)(qb + (size_t)token * 128 + koff);
        float4 q0 = qp[0], q1 = qp[1];
        q[0] = q0.x; q[1] = q0.y; q[2] = q0.z; q[3] = q0.w;
        q[4] = q1.x; q[5] = q1.y; q[6] = q1.z; q[7] = q1.w;
    }

    const float* rp = rpb + head * 169 + (sy - y + 6) * 13 + (sx - xx + 6);
    const int nbase = (bb << 12) + sy * 64 + sx;

    float sc[13];
#pragma unroll
    for (int i = 0; i < 13; i++) {
        int n = g * 13 + i;
        bool ok = n < 49;
        int nn = ok ? n : 48;
        int dy = nn / 7, dx = nn - dy * 7;
        const uint4 kk = *(const uint4*)(kvb + (size_t)(nbase + dy * 64 + dx) * 256 + koff);
        float s = q[0] * lo16(kk.x) + q[1] * hi16(kk.x)
                + q[2] * lo16(kk.y) + q[3] * hi16(kk.y)
                + q[4] * lo16(kk.z) + q[5] * hi16(kk.z)
                + q[6] * lo16(kk.w) + q[7] * hi16(kk.w);
        s += __shfl_xor(s, 1);
        s += __shfl_xor(s, 2);
        sc[i] = ok ? (s + rp[dy * 13 + dx]) : -1e30f;
    }
    float mx = sc[0];
#pragma unroll
    for (int l = 1; l < 13; l++) mx = fmaxf(mx, sc[l]);
    mx = fmaxf(mx, __shfl_xor(mx, 4));
    mx = fmaxf(mx, __shfl_xor(mx, 8));
    float sum = 0.f;
#pragma unroll
    for (int l = 0; l < 13; l++) { sc[l] = __expf(sc[l] - mx); sum += sc[l]; }
    sum += __shfl_xor(sum, 4);
    sum += __shfl_xor(sum, 8);
    float inv = 1.f / sum;

    float o[8];
#pragma unroll
    for (int i = 0; i < 8; i++) o[i] = 0.f;
#pragma unroll
    for (int i = 0; i < 13; i++) {
        int n = g * 13 + i;
        int nn = (n < 49) ? n : 48;
        int dy = nn / 7, dx = nn - dy * 7;
        float p = sc[i] * inv;
        const uint4 vv = *(const uint4*)(kvb + (size_t)(nbase + dy * 64 + dx) * 256 + 128 + koff);
        o[0] += p * lo16(vv.x); o[1] += p * hi16(vv.x);
        o[2] += p * lo16(vv.y); o[3] += p * hi16(vv.y);
        o[4] += p * lo16(vv.z); o[5] += p * hi16(vv.z);
        o[6] += p * lo16(vv.w); o[7] += p * hi16(vv.w);
    }
#pragma unroll
    for (int i = 0; i < 8; i++) {
        o[i] += __shfl_xor(o[i], 4);
        o[i] += __shfl_xor(o[i], 8);
    }
    if (g == 0) {
        uint4 ov;
        ov.x = bfp2(o[0], o[1]); ov.y = bfp2(o[2], o[3]);
        ov.z = bfp2(o[4], o[5]); ov.w = bfp2(o[6], o[7]);
        *(uint4*)(attnb + (size_t)token * 128 + koff) = ov;
    }
}

// ---------------- k3: proj GEMM (K=128, N=128) + residual -> h ----------------
__global__ __launch_bounds__(256) void k3_mfma(bfp16 attnb, fp x, bfp16 wt1, fp wb,
                                               float* __restrict__ h) {
    __shared__ unsigned int lds[8192];
    const int m0 = blockIdx.x * 64;
    const int nb = blockIdx.y * 64;
    const int tid = threadIdx.x;
#pragma unroll
    for (int i = 0; i < 4; i++) {
        int slot = tid + i * 256;
        int m = slot >> 4, c16 = slot & 15;
        const uint4 v4 = *(const uint4*)(attnb + (size_t)(m0 + m) * 128 + c16 * 8);
        *(uint4*)&lds[m * 64 + (c16 ^ (m & 15)) * 4] = v4;
    }
#pragma unroll
    for (int i = 0; i < 4; i++) {
        int slot = tid + i * 256;
        int n = slot >> 4, c16 = slot & 15;
        const uint4 v4 = *(const uint4*)(wt1 + (size_t)(nb + n) * 128 + c16 * 8);
        *(uint4*)&lds[4096 + n * 64 + (c16 ^ (n & 15)) * 4] = v4;
    }
    __syncthreads();

    const int lane = tid & 63, wid = tid >> 6, quad = lane >> 4, l16 = lane & 15;
    const int mrow = wid * 16 + l16;
    f32x4 acc[4];
#pragma unroll
    for (int nt = 0; nt < 4; nt++) acc[nt] = (f32x4){0.f, 0.f, 0.f, 0.f};
#pragma unroll
    for (int kk = 0; kk < 128; kk += 32) {
        int c = (kk >> 3) + quad;
        bf16x8 a = *(bf16x8*)&lds[mrow * 64 + (c ^ l16) * 4];
#pragma unroll
        for (int nt = 0; nt < 4; nt++) {
            bf16x8 bf = *(bf16x8*)&lds[4096 + (nt * 16 + l16) * 64 + (c ^ l16) * 4];
            acc[nt] = __builtin_amdgcn_mfma_f32_16x16x32_bf16(a, bf, acc[nt], 0, 0, 0);
        }
    }
#pragma unroll
    for (int nt = 0; nt < 4; nt++) {
        int col = nb + nt * 16 + l16;
        float bias = wb[col];
#pragma unroll
        for (int r = 0; r < 4; r++) {
            int row = m0 + wid * 16 + quad * 4 + r;
            h[(size_t)row * CDIM + col] = x[(size_t)row * CDIM + col] + acc[nt][r] + bias;
        }
    }
}

// ---------------- k4: fc1 + GELU (A=hn bf16, K=128, N=512) -> y1 bf16 ----------------
__global__ __launch_bounds__(256) void k4_mfma(bfp16 hn, bfp16 wt2, fp wb,
                                               unsigned short* __restrict__ y1) {
    __shared__ unsigned int lds[8192];
    const int m0 = blockIdx.x * 64;
    const int nb = blockIdx.y * 64;
    const int tid = threadIdx.x;
#pragma unroll
    for (int i = 0; i < 4; i++) {
        int slot = tid + i * 256;
        int m = slot >> 4, c16 = slot & 15;
        const uint4 v4 = *(const uint4*)(hn + (size_t)(m0 + m) * CDIM + c16 * 8);
        *(uint4*)&lds[m * 64 + (c16 ^ (m & 15)) * 4] = v4;
    }
#pragma unroll
    for (int i = 0; i < 4; i++) {
        int slot = tid + i * 256;
        int n = slot >> 4, c16 = slot & 15;
        const uint4 v4 = *(const uint4*)(wt2 + (size_t)(nb + n) * 128 + c16 * 8);
        *(uint4*)&lds[4096 + n * 64 + (c16 ^ (n & 15)) * 4] = v4;
    }
    __syncthreads();

    const int lane = tid & 63, wid = tid >> 6, quad = lane >> 4, l16 = lane & 15;
    const int mrow = wid * 16 + l16;
    f32x4 acc[4];
#pragma unroll
    for (int nt = 0; nt < 4; nt++) acc[nt] = (f32x4){0.f, 0.f, 0.f, 0.f};
#pragma unroll
    for (int kk = 0; kk < 128; kk += 32) {
        int c = (kk >> 3) + quad;
        bf16x8 a = *(bf16x8*)&lds[mrow * 64 + (c ^ l16) * 4];
#pragma unroll
        for (int nt = 0; nt < 4; nt++) {
            bf16x8 bf = *(bf16x8*)&lds[4096 + (nt * 16 + l16) * 64 + (c ^ l16) * 4];
            acc[nt] = __builtin_amdgcn_mfma_f32_16x16x32_bf16(a, bf, acc[nt], 0, 0, 0);
        }
    }
#pragma unroll
    for (int nt = 0; nt < 4; nt++) {
        int col = nb + nt * 16 + l16;
        float bias = wb[col];
#pragma unroll
        for (int r = 0; r < 4; r++) {
            int row = m0 + wid * 16 + quad * 4 + r;
            float z = acc[nt][r] + bias;
            y1[(size_t)row * HID + col] = bf1(0.5f * z * (1.f + erff(z * 0.70710678118654752f)));
        }
    }
}

// ---------------- k5: fc2 + residual (K=512 in 4 chunks, N=128) ----------------
__global__ __launch_bounds__(256) void k5_mfma(bfp16 y1, fp h, bfp16 wt3, fp wb,
                                               float* __restrict__ out) {
    __shared__ unsigned int lds[8192];
    const int m0 = blockIdx.x * 64;
    const int nb = blockIdx.y * 64;
    const int tid = threadIdx.x;
    const int lane = tid & 63, wid = tid >> 6, quad = lane >> 4, l16 = lane & 15;
    const int mrow = wid * 16 + l16;
    f32x4 acc[4];
#pragma unroll
    for (int nt = 0; nt < 4; nt++) acc[nt] = (f32x4){0.f, 0.f, 0.f, 0.f};

    for (int kc = 0; kc < 4; kc++) {
        if (kc) __syncthreads();
#pragma unroll
        for (int i = 0; i < 4; i++) {
            int slot = tid + i * 256;
            int m = slot >> 4, c16 = slot & 15;
            const uint4 v4 = *(const uint4*)(y1 + (size_t)(m0 + m) * HID + kc * 128 + c16 * 8);
            *(uint4*)&lds[m * 64 + (c16 ^ (m & 15)) * 4] = v4;
        }
#pragma unroll
        for (int i = 0; i < 4; i++) {
            int slot = tid + i * 256;
            int n = slot >> 4, c16 = slot & 15;
            const uint4 v4 = *(const uint4*)(wt3 + (size_t)(nb + n) * 512 + kc * 128 + c16 * 8);
            *(uint4*)&lds[4096 + n * 64 + (c16 ^ (n & 15)) * 4] = v4;
        }
        __syncthreads();
#pragma unroll
        for (int kk = 0; kk < 128; kk += 32) {
            int c = (kk >> 3) + quad;
            bf16x8 a = *(bf16x8*)&lds[mrow * 64 + (c ^ l16) * 4];
#pragma unroll
            for (int nt = 0; nt < 4; nt++) {
                bf16x8 bf = *(bf16x8*)&lds[4096 + (nt * 16 + l16) * 64 + (c ^ l16) * 4];
                acc[nt] = __builtin_amdgcn_mfma_f32_16x16x32_bf16(a, bf, acc[nt], 0, 0, 0);
            }
        }
    }
#pragma unroll
    for (int nt = 0; nt < 4; nt++) {
        int col = nb + nt * 16 + l16;
        float bias = wb[col];
#pragma unroll
        for (int r = 0; r < 4; r++) {
            int row = m0 + wid * 16 + quad * 4 + r;
            out[(size_t)row * CDIM + col] = h[(size_t)row * CDIM + col] + acc[nt][r] + bias;
        }
    }
}

extern "C" void kernel_launch(void* const* d_in, const int* in_sizes, int n_in,
                              void* d_out, int out_size, void* d_ws, size_t ws_size,
                              hipStream_t stream) {
    fp x      = (fp)d_in[0];
    fp ln1_g  = (fp)d_in[1];
    fp ln1_b  = (fp)d_in[2];
    fp qkv_w  = (fp)d_in[3];
    fp qkv_b  = (fp)d_in[4];
    fp rpb    = (fp)d_in[5];
    fp proj_w = (fp)d_in[6];
    fp proj_b = (fp)d_in[7];
    fp ln2_g  = (fp)d_in[8];
    fp ln2_b  = (fp)d_in[9];
    fp fc1_w  = (fp)d_in[10];
    fp fc1_b  = (fp)d_in[11];
    fp fc2_w  = (fp)d_in[12];
    fp fc2_b  = (fp)d_in[13];
    float* out = (float*)d_out;

    // workspace (floats):
    //   h     f32 [TOKS][128]          2M floats
    //   xn    bf16[TOKS][128]          1M
    //   hn    bf16[TOKS][128]          1M
    //   qb    f32 [TOKS][128]          2M   (dead after k2)
    //   kvb   bf16[TOKS][256]          2M   (dead after k2)
    //   attnb bf16[TOKS][128]          1M   (dead after k3)
    //   wt    bf16[196608]             ~0.1M
    //   y1    bf16[TOKS][512] = 4M floats, aliases qb+kvb exactly
    float* ws = (float*)d_ws;
    float* h  = ws;
    unsigned short* xn = (unsigned short*)(h + (size_t)TOKS * CDIM);
    unsigned short* hn = xn + (size_t)TOKS * CDIM;
    float* qb = (float*)(hn + (size_t)TOKS * CDIM);
    unsigned short* kvb   = (unsigned short*)(qb + (size_t)TOKS * CDIM);
    unsigned short* attnb = kvb + (size_t)TOKS * 256;
    unsigned short* wt    = attnb + (size_t)TOKS * CDIM;
    unsigned short* y1    = (unsigned short*)qb;

    unsigned short* wt0 = wt;            // qkv  [384][128]
    unsigned short* wt1 = wt + 49152;    // proj [128][128]
    unsigned short* wt2 = wt + 65536;    // fc1  [512][128]
    unsigned short* wt3 = wt + 131072;   // fc2  [128][512]

    kw<<<768, 256, 0, stream>>>(qkv_w, proj_w, fc1_w, fc2_w, wt);
    k0_ln<<<TOKS / 8, 256, 0, stream>>>(x, ln1_g, ln1_b, xn);
    k1_mfma<<<dim3(TOKS / 64, 6), 256, 0, stream>>>(xn, wt0, qkv_b, qb, kvb);
    k2_attn<<<TOKS * NH * 16 / 256, 256, 0, stream>>>(qb, kvb, rpb, attnb);
    k3_mfma<<<dim3(TOKS / 64, 2), 256, 0, stream>>>(attnb, x, wt1, proj_b, h);
    k0_ln<<<TOKS / 8, 256, 0, stream>>>(h, ln2_g, ln2_b, hn);
    k4_mfma<<<dim3(TOKS / 64, 8), 256, 0, stream>>>(hn, wt2, fc1_b, y1);
    k5_mfma<<<dim3(TOKS / 64, 2), 256, 0, stream>>>(y1, h, fc2_w == nullptr ? wt3 : wt3, fc2_b, out);
}

// Round 11
// 148.885 us; speedup vs baseline: 1.3066x; 1.0109x over previous
//
#include <hip/hip_runtime.h>
#include <math.h>

#define TOKS 16384
#define CDIM 128
#define NH 4
#define HD 32
#define HID 512
#define QSCALE 0.17677669529663687f
#define LEPS 1e-5f

typedef const float* fp;
typedef const unsigned short* bfp16;
typedef __attribute__((ext_vector_type(8))) short bf16x8;
typedef __attribute__((ext_vector_type(4))) float f32x4;

__device__ inline unsigned int bfp2(float a, float b) {
    unsigned int ua = __float_as_uint(a); ua = (ua + 0x7FFFu + ((ua >> 16) & 1u)) >> 16;
    unsigned int ub = __float_as_uint(b); ub = (ub + 0x7FFFu + ((ub >> 16) & 1u)) >> 16;
    return ua | (ub << 16);
}
__device__ inline unsigned short bf1(float a) {
    unsigned int u = __float_as_uint(a);
    return (unsigned short)((u + 0x7FFFu + ((u >> 16) & 1u)) >> 16);
}
__device__ inline float lo16(unsigned int u) { return __uint_as_float(u << 16); }
__device__ inline float hi16(unsigned int u) { return __uint_as_float(u & 0xFFFF0000u); }

// ---------------- prep: weight convert+transpose (blocks 0..767) + LN1 (blocks 768+) ----
__global__ __launch_bounds__(256) void prep(fp qw, fp pw, fp f1w, fp f2w,
                                            fp x, fp g, fp b,
                                            unsigned short* __restrict__ wt,
                                            unsigned short* __restrict__ xn) {
    const int bid = blockIdx.x;
    if (bid < 768) {
        int e = bid * 256 + threadIdx.x;
        float v;
        if (e < 49152)       { int n = e >> 7,  k = e & 127;          v = qw[(size_t)k * 384 + n]; }
        else if (e < 65536)  { int i = e - 49152;  int n = i >> 7, k = i & 127; v = pw[(size_t)k * 128 + n]; }
        else if (e < 131072) { int i = e - 65536;  int n = i >> 7, k = i & 127; v = f1w[(size_t)k * 512 + n]; }
        else                 { int i = e - 131072; int n = i >> 9, k = i & 511; v = f2w[(size_t)k * 128 + n]; }
        wt[e] = bf1(v);
    } else {
        const int t = threadIdx.x;
        const int row = (bid - 768) * 8 + (t >> 5);
        const int l = t & 31;
        const float4 v = *(const float4*)(x + (size_t)row * CDIM + l * 4);
        float s = v.x + v.y + v.z + v.w;
        float q = v.x * v.x + v.y * v.y + v.z * v.z + v.w * v.w;
#pragma unroll
        for (int m = 16; m >= 1; m >>= 1) { s += __shfl_xor(s, m); q += __shfl_xor(q, m); }
        float mu = s * (1.f / 128.f);
        float rs = rsqrtf(q * (1.f / 128.f) - mu * mu + LEPS);
        const float4 gv = *(const float4*)(g + l * 4);
        const float4 bv = *(const float4*)(b + l * 4);
        float a0 = (v.x - mu) * rs * gv.x + bv.x, a1 = (v.y - mu) * rs * gv.y + bv.y;
        float a2 = (v.z - mu) * rs * gv.z + bv.z, a3 = (v.w - mu) * rs * gv.w + bv.w;
        uint2 o; o.x = bfp2(a0, a1); o.y = bfp2(a2, a3);
        *(uint2*)(xn + (size_t)row * CDIM + l * 4) = o;
    }
}

// ================= MFMA GEMM kernels =================
// k1/k4/k5 tile: 128(M) x 64(N), 256 threads = 4 waves; wave = 32 rows (2 m-frags) x 4 n-tiles.
// LDS: A[128 m][64 dw] + B[64 n][64 dw] bf16, 16B-chunk XOR swizzle; uint4-copy staging.

// ---------------- k1: QKV GEMM (A=xn, K=128, N=384); Q->f32, K/V->bf16 ----------------
__global__ __launch_bounds__(256) void k1_mfma(bfp16 xn, bfp16 wt0, fp wb,
                                               float* __restrict__ qb,
                                               unsigned short* __restrict__ kvb) {
    __shared__ unsigned int lds[12288];
    const int m0 = blockIdx.x * 128;
    const int nb = blockIdx.y * 64;
    const int tid = threadIdx.x;
#pragma unroll
    for (int i = 0; i < 8; i++) {
        int slot = tid + i * 256;
        int m = slot >> 4, c16 = slot & 15;
        const uint4 v4 = *(const uint4*)(xn + (size_t)(m0 + m) * CDIM + c16 * 8);
        *(uint4*)&lds[m * 64 + (c16 ^ (m & 15)) * 4] = v4;
    }
#pragma unroll
    for (int i = 0; i < 4; i++) {
        int slot = tid + i * 256;
        int n = slot >> 4, c16 = slot & 15;
        const uint4 v4 = *(const uint4*)(wt0 + (size_t)(nb + n) * 128 + c16 * 8);
        *(uint4*)&lds[8192 + n * 64 + (c16 ^ (n & 15)) * 4] = v4;
    }
    __syncthreads();

    const int lane = tid & 63, wid = tid >> 6, quad = lane >> 4, l16 = lane & 15;
    f32x4 acc[2][4];
#pragma unroll
    for (int mt = 0; mt < 2; mt++)
#pragma unroll
        for (int nt = 0; nt < 4; nt++) acc[mt][nt] = (f32x4){0.f, 0.f, 0.f, 0.f};
#pragma unroll
    for (int kk = 0; kk < 4; kk++) {
        int c = kk * 4 + quad;
        bf16x8 a0 = *(bf16x8*)&lds[(wid * 32 + l16) * 64 + (c ^ l16) * 4];
        bf16x8 a1 = *(bf16x8*)&lds[(wid * 32 + 16 + l16) * 64 + (c ^ l16) * 4];
#pragma unroll
        for (int nt = 0; nt < 4; nt++) {
            bf16x8 bf = *(bf16x8*)&lds[8192 + (nt * 16 + l16) * 64 + (c ^ l16) * 4];
            acc[0][nt] = __builtin_amdgcn_mfma_f32_16x16x32_bf16(a0, bf, acc[0][nt], 0, 0, 0);
            acc[1][nt] = __builtin_amdgcn_mfma_f32_16x16x32_bf16(a1, bf, acc[1][nt], 0, 0, 0);
        }
    }
#pragma unroll
    for (int nt = 0; nt < 4; nt++) {
        int col = nb + nt * 16 + l16;
        float bias = wb[col];
#pragma unroll
        for (int mt = 0; mt < 2; mt++)
#pragma unroll
            for (int r = 0; r < 4; r++) {
                int row = m0 + wid * 32 + mt * 16 + quad * 4 + r;
                float vres = acc[mt][nt][r] + bias;
                if (col < 128)
                    qb[(size_t)row * 128 + col] = vres * QSCALE;
                else if (col < 256)
                    kvb[(size_t)row * 256 + (col - 128)] = bf1(vres);
                else
                    kvb[(size_t)row * 256 + 128 + (col - 256)] = bf1(vres);
            }
    }
}

// ---------------- k2: neighborhood attention, 16 lanes per (token, head) ----------------
__global__ __launch_bounds__(256) void k2_attn(const float* __restrict__ qb,
                                               const unsigned short* __restrict__ kvb,
                                               fp rpb, unsigned short* __restrict__ attnb) {
    const int gid = blockIdx.x * 256 + threadIdx.x;   // 1048576
    const int d = gid & 3;
    const int g = (gid >> 2) & 3;
    const int head = (gid >> 4) & 3;
    const int token = gid >> 6;
    const int bb = token >> 12;
    const int y = (token >> 6) & 63;
    const int xx = token & 63;
    const int sy = min(max(y - 3, 0), 57);
    const int sx = min(max(xx - 3, 0), 57);

    const int koff = head * HD + d * 8;
    float q[8];
    {
        const float4* qp = (const float4*)(qb + (size_t)token * 128 + koff);
        float4 q0 = qp[0], q1 = qp[1];
        q[0] = q0.x; q[1] = q0.y; q[2] = q0.z; q[3] = q0.w;
        q[4] = q1.x; q[5] = q1.y; q[6] = q1.z; q[7] = q1.w;
    }

    const float* rp = rpb + head * 169 + (sy - y + 6) * 13 + (sx - xx + 6);
    const int nbase = (bb << 12) + sy * 64 + sx;

    float sc[13];
#pragma unroll
    for (int i = 0; i < 13; i++) {
        int n = g * 13 + i;
        bool ok = n < 49;
        int nn = ok ? n : 48;
        int dy = nn / 7, dx = nn - dy * 7;
        const uint4 kk = *(const uint4*)(kvb + (size_t)(nbase + dy * 64 + dx) * 256 + koff);
        float s = q[0] * lo16(kk.x) + q[1] * hi16(kk.x)
                + q[2] * lo16(kk.y) + q[3] * hi16(kk.y)
                + q[4] * lo16(kk.z) + q[5] * hi16(kk.z)
                + q[6] * lo16(kk.w) + q[7] * hi16(kk.w);
        s += __shfl_xor(s, 1);
        s += __shfl_xor(s, 2);
        sc[i] = ok ? (s + rp[dy * 13 + dx]) : -1e30f;
    }
    float mx = sc[0];
#pragma unroll
    for (int l = 1; l < 13; l++) mx = fmaxf(mx, sc[l]);
    mx = fmaxf(mx, __shfl_xor(mx, 4));
    mx = fmaxf(mx, __shfl_xor(mx, 8));
    float sum = 0.f;
#pragma unroll
    for (int l = 0; l < 13; l++) { sc[l] = __expf(sc[l] - mx); sum += sc[l]; }
    sum += __shfl_xor(sum, 4);
    sum += __shfl_xor(sum, 8);
    float inv = 1.f / sum;

    float o[8];
#pragma unroll
    for (int i = 0; i < 8; i++) o[i] = 0.f;
#pragma unroll
    for (int i = 0; i < 13; i++) {
        int n = g * 13 + i;
        int nn = (n < 49) ? n : 48;
        int dy = nn / 7, dx = nn - dy * 7;
        float p = sc[i] * inv;
        const uint4 vv = *(const uint4*)(kvb + (size_t)(nbase + dy * 64 + dx) * 256 + 128 + koff);
        o[0] += p * lo16(vv.x); o[1] += p * hi16(vv.x);
        o[2] += p * lo16(vv.y); o[3] += p * hi16(vv.y);
        o[4] += p * lo16(vv.z); o[5] += p * hi16(vv.z);
        o[6] += p * lo16(vv.w); o[7] += p * hi16(vv.w);
    }
#pragma unroll
    for (int i = 0; i < 8; i++) {
        o[i] += __shfl_xor(o[i], 4);
        o[i] += __shfl_xor(o[i], 8);
    }
    if (g == 0) {
        uint4 ov;
        ov.x = bfp2(o[0], o[1]); ov.y = bfp2(o[2], o[3]);
        ov.z = bfp2(o[4], o[5]); ov.w = bfp2(o[6], o[7]);
        *(uint4*)(attnb + (size_t)token * 128 + koff) = ov;
    }
}

// ---------------- k3: proj GEMM (64x128 tile) + residual + fused LN2 -> h, hn ----------
__global__ __launch_bounds__(256) void k3_mfma(bfp16 attnb, fp x, bfp16 wt1, fp pb,
                                               fp g2, fp b2,
                                               float* __restrict__ h,
                                               unsigned short* __restrict__ hn) {
    __shared__ unsigned int lds[12288];   // A 4096 + B 8192
    const int m0 = blockIdx.x * 64;
    const int tid = threadIdx.x;
#pragma unroll
    for (int i = 0; i < 4; i++) {
        int slot = tid + i * 256;
        int m = slot >> 4, c16 = slot & 15;
        const uint4 v4 = *(const uint4*)(attnb + (size_t)(m0 + m) * CDIM + c16 * 8);
        *(uint4*)&lds[m * 64 + (c16 ^ (m & 15)) * 4] = v4;
    }
#pragma unroll
    for (int i = 0; i < 8; i++) {
        int slot = tid + i * 256;
        int n = slot >> 4, c16 = slot & 15;
        const uint4 v4 = *(const uint4*)(wt1 + (size_t)n * 128 + c16 * 8);
        *(uint4*)&lds[4096 + n * 64 + (c16 ^ (n & 15)) * 4] = v4;
    }
    __syncthreads();

    const int lane = tid & 63, wid = tid >> 6, quad = lane >> 4, l16 = lane & 15;
    const int mrow = wid * 16 + l16;
    f32x4 acc[8];
#pragma unroll
    for (int nt = 0; nt < 8; nt++) acc[nt] = (f32x4){0.f, 0.f, 0.f, 0.f};
#pragma unroll
    for (int kk = 0; kk < 4; kk++) {
        int c = kk * 4 + quad;
        bf16x8 a = *(bf16x8*)&lds[mrow * 64 + (c ^ l16) * 4];
#pragma unroll
        for (int nt = 0; nt < 8; nt++) {
            bf16x8 bf = *(bf16x8*)&lds[4096 + (nt * 16 + l16) * 64 + (c ^ l16) * 4];
            acc[nt] = __builtin_amdgcn_mfma_f32_16x16x32_bf16(a, bf, acc[nt], 0, 0, 0);
        }
    }
    // epilogue: residual + h write + in-register LN2 stats per row
    float s[4] = {0.f, 0.f, 0.f, 0.f}, q[4] = {0.f, 0.f, 0.f, 0.f};
#pragma unroll
    for (int nt = 0; nt < 8; nt++) {
        int col = nt * 16 + l16;
        float bias = pb[col];
#pragma unroll
        for (int r = 0; r < 4; r++) {
            int row = m0 + wid * 16 + quad * 4 + r;
            float hv = x[(size_t)row * CDIM + col] + acc[nt][r] + bias;
            h[(size_t)row * CDIM + col] = hv;
            acc[nt][r] = hv;
            s[r] += hv; q[r] += hv * hv;
        }
    }
#pragma unroll
    for (int m = 1; m <= 8; m <<= 1) {
#pragma unroll
        for (int r = 0; r < 4; r++) {
            s[r] += __shfl_xor(s[r], m);
            q[r] += __shfl_xor(q[r], m);
        }
    }
    float mu[4], rs[4];
#pragma unroll
    for (int r = 0; r < 4; r++) {
        mu[r] = s[r] * (1.f / 128.f);
        rs[r] = rsqrtf(q[r] * (1.f / 128.f) - mu[r] * mu[r] + LEPS);
    }
#pragma unroll
    for (int nt = 0; nt < 8; nt++) {
        int col = nt * 16 + l16;
        float gg = g2[col], bb = b2[col];
#pragma unroll
        for (int r = 0; r < 4; r++) {
            int row = m0 + wid * 16 + quad * 4 + r;
            hn[(size_t)row * CDIM + col] = bf1((acc[nt][r] - mu[r]) * rs[r] * gg + bb);
        }
    }
}

// ---------------- k4: fc1 + GELU (A=hn, K=128, N=512) -> y1 bf16 ----------------
__global__ __launch_bounds__(256) void k4_mfma(bfp16 hn, bfp16 wt2, fp wb,
                                               unsigned short* __restrict__ y1) {
    __shared__ unsigned int lds[12288];
    const int m0 = blockIdx.x * 128;
    const int nb = blockIdx.y * 64;
    const int tid = threadIdx.x;
#pragma unroll
    for (int i = 0; i < 8; i++) {
        int slot = tid + i * 256;
        int m = slot >> 4, c16 = slot & 15;
        const uint4 v4 = *(const uint4*)(hn + (size_t)(m0 + m) * CDIM + c16 * 8);
        *(uint4*)&lds[m * 64 + (c16 ^ (m & 15)) * 4] = v4;
    }
#pragma unroll
    for (int i = 0; i < 4; i++) {
        int slot = tid + i * 256;
        int n = slot >> 4, c16 = slot & 15;
        const uint4 v4 = *(const uint4*)(wt2 + (size_t)(nb + n) * 128 + c16 * 8);
        *(uint4*)&lds[8192 + n * 64 + (c16 ^ (n & 15)) * 4] = v4;
    }
    __syncthreads();

    const int lane = tid & 63, wid = tid >> 6, quad = lane >> 4, l16 = lane & 15;
    f32x4 acc[2][4];
#pragma unroll
    for (int mt = 0; mt < 2; mt++)
#pragma unroll
        for (int nt = 0; nt < 4; nt++) acc[mt][nt] = (f32x4){0.f, 0.f, 0.f, 0.f};
#pragma unroll
    for (int kk = 0; kk < 4; kk++) {
        int c = kk * 4 + quad;
        bf16x8 a0 = *(bf16x8*)&lds[(wid * 32 + l16) * 64 + (c ^ l16) * 4];
        bf16x8 a1 = *(bf16x8*)&lds[(wid * 32 + 16 + l16) * 64 + (c ^ l16) * 4];
#pragma unroll
        for (int nt = 0; nt < 4; nt++) {
            bf16x8 bf = *(bf16x8*)&lds[8192 + (nt * 16 + l16) * 64 + (c ^ l16) * 4];
            acc[0][nt] = __builtin_amdgcn_mfma_f32_16x16x32_bf16(a0, bf, acc[0][nt], 0, 0, 0);
            acc[1][nt] = __builtin_amdgcn_mfma_f32_16x16x32_bf16(a1, bf, acc[1][nt], 0, 0, 0);
        }
    }
#pragma unroll
    for (int nt = 0; nt < 4; nt++) {
        int col = nb + nt * 16 + l16;
        float bias = wb[col];
#pragma unroll
        for (int mt = 0; mt < 2; mt++)
#pragma unroll
            for (int r = 0; r < 4; r++) {
                int row = m0 + wid * 32 + mt * 16 + quad * 4 + r;
                float z = acc[mt][nt][r] + bias;
                y1[(size_t)row * HID + col] = bf1(0.5f * z * (1.f + erff(z * 0.70710678118654752f)));
            }
    }
}

// ---------------- k5: fc2 + residual (K=512 in 4 chunks, N=128) ----------------
__global__ __launch_bounds__(256) void k5_mfma(bfp16 y1, fp h, bfp16 wt3, fp wb,
                                               float* __restrict__ out) {
    __shared__ unsigned int lds[12288];
    const int m0 = blockIdx.x * 128;
    const int nb = blockIdx.y * 64;
    const int tid = threadIdx.x;
    const int lane = tid & 63, wid = tid >> 6, quad = lane >> 4, l16 = lane & 15;
    f32x4 acc[2][4];
#pragma unroll
    for (int mt = 0; mt < 2; mt++)
#pragma unroll
        for (int nt = 0; nt < 4; nt++) acc[mt][nt] = (f32x4){0.f, 0.f, 0.f, 0.f};

    for (int kc = 0; kc < 4; kc++) {
        if (kc) __syncthreads();
#pragma unroll
        for (int i = 0; i < 8; i++) {
            int slot = tid + i * 256;
            int m = slot >> 4, c16 = slot & 15;
            const uint4 v4 = *(const uint4*)(y1 + (size_t)(m0 + m) * HID + kc * 128 + c16 * 8);
            *(uint4*)&lds[m * 64 + (c16 ^ (m & 15)) * 4] = v4;
        }
#pragma unroll
        for (int i = 0; i < 4; i++) {
            int slot = tid + i * 256;
            int n = slot >> 4, c16 = slot & 15;
            const uint4 v4 = *(const uint4*)(wt3 + (size_t)(nb + n) * 512 + kc * 128 + c16 * 8);
            *(uint4*)&lds[8192 + n * 64 + (c16 ^ (n & 15)) * 4] = v4;
        }
        __syncthreads();
#pragma unroll
        for (int kk = 0; kk < 4; kk++) {
            int c = kk * 4 + quad;
            bf16x8 a0 = *(bf16x8*)&lds[(wid * 32 + l16) * 64 + (c ^ l16) * 4];
            bf16x8 a1 = *(bf16x8*)&lds[(wid * 32 + 16 + l16) * 64 + (c ^ l16) * 4];
#pragma unroll
            for (int nt = 0; nt < 4; nt++) {
                bf16x8 bf = *(bf16x8*)&lds[8192 + (nt * 16 + l16) * 64 + (c ^ l16) * 4];
                acc[0][nt] = __builtin_amdgcn_mfma_f32_16x16x32_bf16(a0, bf, acc[0][nt], 0, 0, 0);
                acc[1][nt] = __builtin_amdgcn_mfma_f32_16x16x32_bf16(a1, bf, acc[1][nt], 0, 0, 0);
            }
        }
    }
#pragma unroll
    for (int nt = 0; nt < 4; nt++) {
        int col = nb + nt * 16 + l16;
        float bias = wb[col];
#pragma unroll
        for (int mt = 0; mt < 2; mt++)
#pragma unroll
            for (int r = 0; r < 4; r++) {
                int row = m0 + wid * 32 + mt * 16 + quad * 4 + r;
                out[(size_t)row * CDIM + col] = h[(size_t)row * CDIM + col] + acc[mt][nt][r] + bias;
            }
    }
}

extern "C" void kernel_launch(void* const* d_in, const int* in_sizes, int n_in,
                              void* d_out, int out_size, void* d_ws, size_t ws_size,
                              hipStream_t stream) {
    fp x      = (fp)d_in[0];
    fp ln1_g  = (fp)d_in[1];
    fp ln1_b  = (fp)d_in[2];
    fp qkv_w  = (fp)d_in[3];
    fp qkv_b  = (fp)d_in[4];
    fp rpb    = (fp)d_in[5];
    fp proj_w = (fp)d_in[6];
    fp proj_b = (fp)d_in[7];
    fp ln2_g  = (fp)d_in[8];
    fp ln2_b  = (fp)d_in[9];
    fp fc1_w  = (fp)d_in[10];
    fp fc1_b  = (fp)d_in[11];
    fp fc2_w  = (fp)d_in[12];
    fp fc2_b  = (fp)d_in[13];
    float* out = (float*)d_out;

    float* ws = (float*)d_ws;
    float* h  = ws;
    unsigned short* xn = (unsigned short*)(h + (size_t)TOKS * CDIM);
    unsigned short* hn = xn + (size_t)TOKS * CDIM;
    float* qb = (float*)(hn + (size_t)TOKS * CDIM);
    unsigned short* kvb   = (unsigned short*)(qb + (size_t)TOKS * CDIM);
    unsigned short* attnb = kvb + (size_t)TOKS * 256;
    unsigned short* wt    = attnb + (size_t)TOKS * CDIM;
    unsigned short* y1    = (unsigned short*)qb;   // aliases qb+kvb (dead by k4)

    unsigned short* wt0 = wt;            // qkv  [384][128]
    unsigned short* wt1 = wt + 49152;    // proj [128][128]
    unsigned short* wt2 = wt + 65536;    // fc1  [512][128]
    unsigned short* wt3 = wt + 131072;   // fc2  [128][512]

    prep<<<768 + TOKS / 8, 256, 0, stream>>>(qkv_w, proj_w, fc1_w, fc2_w, x, ln1_g, ln1_b, wt, xn);
    k1_mfma<<<dim3(TOKS / 128, 6), 256, 0, stream>>>(xn, wt0, qkv_b, qb, kvb);
    k2_attn<<<TOKS * NH * 16 / 256, 256, 0, stream>>>(qb, kvb, rpb, attnb);
    k3_mfma<<<TOKS / 64, 256, 0, stream>>>(attnb, x, wt1, proj_b, ln2_g, ln2_b, h, hn);
    k4_mfma<<<dim3(TOKS / 128, 8), 256, 0, stream>>>(hn, wt2, fc1_b, y1);
    k5_mfma<<<dim3(TOKS / 128, 2), 256, 0, stream>>>(y1, h, wt3, fc2_b, out);
}